// Round 2
// baseline (454.273 us; speedup 1.0000x reference)
//
#include <hip/hip_runtime.h>
#include <hip/hip_bf16.h>

#define N 2048

using f32x4  = __attribute__((ext_vector_type(4))) float;
using short8 = __attribute__((ext_vector_type(8))) short;

// async global->LDS, 16B per lane; LDS dest = wave-uniform base + lane*16
#define GLOAD_LDS16(dst, src)                                                        \
  __builtin_amdgcn_global_load_lds((const __attribute__((address_space(1))) void*)(src), \
                                   (__attribute__((address_space(3))) void*)(dst), 16, 0, 0)

// ---------------------------------------------------------------------------
// Kernel 0: transpose W2 [32][128] -> W2t [128][32] so the MLP inner loop
// reads contiguous, wave-uniform rows (scalar-load friendly).
// ---------------------------------------------------------------------------
__global__ void transpose_w2(const float* __restrict__ W2, float* __restrict__ W2t) {
  int t = blockIdx.x * 256 + threadIdx.x;   // 4096 = 32*128
  int o = t >> 7;                           // 0..31
  int k = t & 127;                          // 0..127
  W2t[k * 32 + o] = W2[t];
}

// ---------------------------------------------------------------------------
// Kernel 1: build A = K^T in bf16.  A[j][i] = v(x_i, x_j) for i <= j, else 0.
// A is lower-triangular (row j has nonzeros in cols 0..j).
// One thread per (i,j); i contiguous -> coalesced stores.
// ---------------------------------------------------------------------------
__global__ __launch_bounds__(256) void build_A(
    const float* __restrict__ x,
    const float* __restrict__ W1,    // [128][2]
    const float* __restrict__ b1,    // [128]
    const float* __restrict__ W2t,   // [128][32]  (k-major)
    const float* __restrict__ b2,    // [32]
    const float* __restrict__ W3,    // [32]
    const float* __restrict__ b3,    // [1]
    __hip_bfloat16* __restrict__ A)  // [N][N]
{
  const int i = blockIdx.x * 256 + threadIdx.x;
  const int j = blockIdx.y;
  if (i > j) {
    A[(size_t)j * N + i] = __float2bfloat16(0.0f);
    return;
  }
  const float xi = x[i];
  const float xj = x[j];

  float acc[32];
#pragma unroll
  for (int o = 0; o < 32; ++o) acc[o] = b2[o];

  for (int k = 0; k < 128; ++k) {
    const float t = fmaf(W1[2 * k], xi, fmaf(W1[2 * k + 1], xj, b1[k]));
    const float h = __builtin_amdgcn_rcpf(1.0f + __expf(-t));   // sigmoid
    const float* w = W2t + (k << 5);                            // uniform row, 128B
#pragma unroll
    for (int o = 0; o < 32; ++o) acc[o] = fmaf(h, w[o], acc[o]);
  }

  float v = b3[0];
#pragma unroll
  for (int o = 0; o < 32; ++o) v = fmaf(fmaxf(acc[o], 0.0f), W3[o], v);

  A[(size_t)j * N + i] = __float2bfloat16(v);
}

// ---------------------------------------------------------------------------
// Kernel 2: C = A * A^T  (NT GEMM, both operands = A, row-major bf16).
// m97 structure: 128x128 tile, BK=32, 4 waves (2x2), 16x16x32 bf16 MFMA,
// global_load_lds width 16.  Triangular A -> k-loop clipped at min(m0,n0)+128.
// ---------------------------------------------------------------------------
__global__ __launch_bounds__(256) void gemm_ata(
    const __hip_bfloat16* __restrict__ A, float* __restrict__ C)
{
  __shared__ __align__(16) __hip_bfloat16 As[128 * 32];  // 8 KB
  __shared__ __align__(16) __hip_bfloat16 Bs[128 * 32];  // 8 KB

  const int m0 = blockIdx.y * 128;
  const int n0 = blockIdx.x * 128;
  const int tid = threadIdx.x;
  const int w  = tid >> 6;
  const int l  = tid & 63;
  const int wr = (w >> 1) * 64;   // wave row offset in tile
  const int wc = (w & 1) * 64;    // wave col offset in tile
  const int lm = l & 15;
  const int lk = l >> 4;          // 0..3

  f32x4 acc[4][4];
#pragma unroll
  for (int m = 0; m < 4; ++m)
#pragma unroll
    for (int n = 0; n < 4; ++n)
      acc[m][n] = (f32x4){0.f, 0.f, 0.f, 0.f};

  const int mn = m0 < n0 ? m0 : n0;
  const int ktiles = (mn + 128) >> 5;   // k only needs to reach min(m0,n0)+127

  // staging: per wave-instruction 64 lanes x 16B = 1KB = 16 rows of 64B
  const int srow = l >> 2;          // 0..15
  const int scol = (l & 3) * 8;     // element offset (8 bf16 = 16B)

  for (int kt = 0; kt < ktiles; ++kt) {
    const int k0 = kt * 32;
    __syncthreads();   // previous compute done before overwriting LDS
#pragma unroll
    for (int c = 0; c < 2; ++c) {
      const int r0 = (w * 2 + c) * 16;   // 0..112
      const __hip_bfloat16* ga = A + (size_t)(m0 + r0 + srow) * N + k0 + scol;
      const __hip_bfloat16* gb = A + (size_t)(n0 + r0 + srow) * N + k0 + scol;
      GLOAD_LDS16(As + r0 * 32, ga);
      GLOAD_LDS16(Bs + r0 * 32, gb);
    }
    __syncthreads();   // implies vmcnt(0): staged data visible

    short8 af[4], bfr[4];
#pragma unroll
    for (int m = 0; m < 4; ++m)
      af[m] = *(const short8*)(As + (wr + m * 16 + lm) * 32 + lk * 8);
#pragma unroll
    for (int n = 0; n < 4; ++n)
      bfr[n] = *(const short8*)(Bs + (wc + n * 16 + lm) * 32 + lk * 8);

#pragma unroll
    for (int m = 0; m < 4; ++m)
#pragma unroll
      for (int n = 0; n < 4; ++n)
        acc[m][n] = __builtin_amdgcn_mfma_f32_16x16x32_bf16(af[m], bfr[n], acc[m][n], 0, 0, 0);
  }

  // C/D layout (verified m89/m91): col = lane&15, row = (lane>>4)*4 + reg
#pragma unroll
  for (int m = 0; m < 4; ++m) {
    const int row = m0 + wr + m * 16 + lk * 4;
#pragma unroll
    for (int n = 0; n < 4; ++n) {
      const int col = n0 + wc + n * 16 + lm;
#pragma unroll
      for (int r = 0; r < 4; ++r)
        C[(size_t)(row + r) * N + col] = acc[m][n][r];
    }
  }
}

// ---------------------------------------------------------------------------
extern "C" void kernel_launch(void* const* d_in, const int* in_sizes, int n_in,
                              void* d_out, int out_size, void* d_ws, size_t ws_size,
                              hipStream_t stream) {
  const float* x  = (const float*)d_in[0];
  const float* W1 = (const float*)d_in[1];
  const float* b1 = (const float*)d_in[2];
  const float* W2 = (const float*)d_in[3];
  const float* b2 = (const float*)d_in[4];
  const float* W3 = (const float*)d_in[5];
  const float* b3 = (const float*)d_in[6];
  float* C = (float*)d_out;

  // workspace: [0,16KB) = W2t (128*32 f32); [16KB, 16KB+8MB) = A (bf16 N*N)
  float* W2t = (float*)d_ws;
  __hip_bfloat16* A = (__hip_bfloat16*)((char*)d_ws + 16384);

  transpose_w2<<<dim3(16), dim3(256), 0, stream>>>(W2, W2t);
  build_A<<<dim3(N / 256, N), dim3(256), 0, stream>>>(x, W1, b1, W2t, b2, W3, b3, A);
  gemm_ata<<<dim3(N / 128, N / 128), dim3(256), 0, stream>>>(A, C);
}

// Round 3
// 219.351 us; speedup vs baseline: 2.0710x; 2.0710x over previous
//
#include <hip/hip_runtime.h>
#include <hip/hip_bf16.h>

#define N 2048

using f32x4  = __attribute__((ext_vector_type(4))) float;
using short8 = __attribute__((ext_vector_type(8))) short;

// async global->LDS, 16B per lane; LDS dest = wave-uniform base + lane*16
#define GLOAD_LDS16(dst, src)                                                        \
  __builtin_amdgcn_global_load_lds((const __attribute__((address_space(1))) void*)(src), \
                                   (__attribute__((address_space(3))) void*)(dst), 16, 0, 0)

// fp32 -> bf16 bits, RNE (inputs are finite sigmoid/MLP values; no NaN path)
__device__ __forceinline__ short f2bf(float f) {
  unsigned u = __builtin_bit_cast(unsigned, f);
  u += 0x7fffu + ((u >> 16) & 1u);
  return (short)(u >> 16);
}

// ---------------------------------------------------------------------------
// Kernel 0: W2 [32][128] f32 -> bf16 (row-major; this IS B^T for the MFMA).
// ---------------------------------------------------------------------------
__global__ void w2_to_bf16(const float* __restrict__ W2, __hip_bfloat16* __restrict__ W2b) {
  int t = blockIdx.x * 256 + threadIdx.x;   // 4096
  W2b[t] = __float2bfloat16(W2[t]);
}

// ---------------------------------------------------------------------------
// Kernel 1: build A = K^T in bf16 with MFMA layer-2.
// Block = 16(i) x 16(j) pair tile, 4 waves; wave w owns j = j0+4w .. j0+4w+3.
// Per wave m-group m (j-row): M=16 pairs (i0..i0+15), N=32 outputs, K=128.
// Lane l computes h for A-frag slots {row=l&15, k=(l>>4)*8+e} -- the exact
// fragment mapping verified end-to-end by gemm_ata below.
// ---------------------------------------------------------------------------
__global__ __launch_bounds__(256) void build_A_mfma(
    const float* __restrict__ x,
    const float* __restrict__ W1,              // [128][2]
    const float* __restrict__ b1,              // [128]
    const __hip_bfloat16* __restrict__ W2b,    // [32][128] bf16
    const float* __restrict__ b2,              // [32]
    const float* __restrict__ W3,              // [32]
    const float* __restrict__ b3,              // [1]
    __hip_bfloat16* __restrict__ A)            // [N][N], A[j][i]
{
  const int bi = blockIdx.x, bj = blockIdx.y;
  const int i0 = bi * 16, j0 = bj * 16;
  const int tid = threadIdx.x;

  if (bi > bj) {  // strictly-lower tile of A (all i > j): zeros (block-uniform)
    A[(size_t)(j0 + (tid >> 4)) * N + i0 + (tid & 15)] = __float2bfloat16(0.0f);
    return;
  }

  __shared__ float w1s[256];   // [k][2]
  __shared__ float b1s[128];
  w1s[tid] = W1[tid];
  if (tid < 128) b1s[tid] = b1[tid];
  __syncthreads();

  const int w  = tid >> 6;
  const int l  = tid & 63;
  const int lm = l & 15;       // A-frag row / C col
  const int lk = l >> 4;       // k-block-of-8 / C row-group

  const float xi = x[i0 + lm];
  float xj[4];
#pragma unroll
  for (int m = 0; m < 4; ++m) xj[m] = x[j0 + w * 4 + m];

  // W2 fragments (B^T row-major): lane holds W2[o=g*16+lm][kb*32 + lk*8 .. +7]
  short8 wf[2][4];
#pragma unroll
  for (int g = 0; g < 2; ++g)
#pragma unroll
    for (int kb = 0; kb < 4; ++kb)
      wf[g][kb] = *(const short8*)(W2b + (g * 16 + lm) * 128 + kb * 32 + lk * 8);

  float b2v[2] = {b2[lm], b2[16 + lm]};
  f32x4 acc[4][2];
#pragma unroll
  for (int m = 0; m < 4; ++m)
#pragma unroll
    for (int g = 0; g < 2; ++g)
      acc[m][g] = (f32x4){b2v[g], b2v[g], b2v[g], b2v[g]};

  for (int kb = 0; kb < 4; ++kb) {
    float w1a[8], w1b[8], bb[8];
#pragma unroll
    for (int e = 0; e < 8; ++e) {
      const int k = kb * 32 + lk * 8 + e;
      w1a[e] = w1s[2 * k];
      w1b[e] = w1s[2 * k + 1];
      bb[e]  = b1s[k];
    }
#pragma unroll
    for (int m = 0; m < 4; ++m) {
      short8 af;
#pragma unroll
      for (int e = 0; e < 8; ++e) {
        const float t  = fmaf(w1a[e], xi, fmaf(w1b[e], xj[m], bb[e]));
        const float ex = __expf(-t);
        const float h  = __builtin_amdgcn_rcpf(1.0f + ex);   // sigmoid
        af[e] = f2bf(h);
      }
      acc[m][0] = __builtin_amdgcn_mfma_f32_16x16x32_bf16(af, wf[0][kb], acc[m][0], 0, 0, 0);
      acc[m][1] = __builtin_amdgcn_mfma_f32_16x16x32_bf16(af, wf[1][kb], acc[m][1], 0, 0, 0);
    }
  }

  // Epilogue: v = b3 + sum_o relu(layer2[pair][o]) * W3[o]
  // C/D: row(pair) = lk*4 + r, col(o) = lm (+16 for g=1)
  const float w3a = W3[lm], w3b = W3[16 + lm];
  const float b3v = b3[0];
  const int   rsel = l & 3;

#pragma unroll
  for (int m = 0; m < 4; ++m) {
    const int j = j0 + w * 4 + m;
    float v[4];
#pragma unroll
    for (int r = 0; r < 4; ++r) {
      float s = fmaf(fmaxf(acc[m][0][r], 0.0f), w3a,
                     fmaxf(acc[m][1][r], 0.0f) * w3b);
      s += __shfl_xor(s, 1);
      s += __shfl_xor(s, 2);
      s += __shfl_xor(s, 4);
      s += __shfl_xor(s, 8);   // all 16 lanes of the col-group now hold the dot
      v[r] = s + b3v;
    }
    const float sv = rsel == 0 ? v[0] : rsel == 1 ? v[1] : rsel == 2 ? v[2] : v[3];
    if (lm < 4) {              // 16 storing lanes cover i-offsets 0..15
      const int i = i0 + lk * 4 + rsel;
      A[(size_t)j * N + i] = (i <= j) ? __float2bfloat16(sv) : __float2bfloat16(0.0f);
    }
  }
}

// ---------------------------------------------------------------------------
// Kernel 2: C = A * A^T  (NT GEMM, both operands = A, row-major bf16).
// m97 structure: 128x128 tile, BK=32, 4 waves (2x2), 16x16x32 bf16 MFMA,
// global_load_lds width 16.  Triangular A -> k-loop clipped at min(m0,n0)+128.
// ---------------------------------------------------------------------------
__global__ __launch_bounds__(256) void gemm_ata(
    const __hip_bfloat16* __restrict__ A, float* __restrict__ C)
{
  __shared__ __align__(16) __hip_bfloat16 As[128 * 32];  // 8 KB
  __shared__ __align__(16) __hip_bfloat16 Bs[128 * 32];  // 8 KB

  const int m0 = blockIdx.y * 128;
  const int n0 = blockIdx.x * 128;
  const int tid = threadIdx.x;
  const int w  = tid >> 6;
  const int l  = tid & 63;
  const int wr = (w >> 1) * 64;
  const int wc = (w & 1) * 64;
  const int lm = l & 15;
  const int lk = l >> 4;

  f32x4 acc[4][4];
#pragma unroll
  for (int m = 0; m < 4; ++m)
#pragma unroll
    for (int n = 0; n < 4; ++n)
      acc[m][n] = (f32x4){0.f, 0.f, 0.f, 0.f};

  const int mn = m0 < n0 ? m0 : n0;
  const int ktiles = (mn + 128) >> 5;

  const int srow = l >> 2;
  const int scol = (l & 3) * 8;

  for (int kt = 0; kt < ktiles; ++kt) {
    const int k0 = kt * 32;
    __syncthreads();
#pragma unroll
    for (int c = 0; c < 2; ++c) {
      const int r0 = (w * 2 + c) * 16;
      const __hip_bfloat16* ga = A + (size_t)(m0 + r0 + srow) * N + k0 + scol;
      const __hip_bfloat16* gb = A + (size_t)(n0 + r0 + srow) * N + k0 + scol;
      GLOAD_LDS16(As + r0 * 32, ga);
      GLOAD_LDS16(Bs + r0 * 32, gb);
    }
    __syncthreads();

    short8 af[4], bfr[4];
#pragma unroll
    for (int m = 0; m < 4; ++m)
      af[m] = *(const short8*)(As + (wr + m * 16 + lm) * 32 + lk * 8);
#pragma unroll
    for (int n = 0; n < 4; ++n)
      bfr[n] = *(const short8*)(Bs + (wc + n * 16 + lm) * 32 + lk * 8);

#pragma unroll
    for (int m = 0; m < 4; ++m)
#pragma unroll
      for (int n = 0; n < 4; ++n)
        acc[m][n] = __builtin_amdgcn_mfma_f32_16x16x32_bf16(af[m], bfr[n], acc[m][n], 0, 0, 0);
  }

#pragma unroll
  for (int m = 0; m < 4; ++m) {
    const int row = m0 + wr + m * 16 + lk * 4;
#pragma unroll
    for (int n = 0; n < 4; ++n) {
      const int col = n0 + wc + n * 16 + lm;
#pragma unroll
      for (int r = 0; r < 4; ++r)
        C[(size_t)(row + r) * N + col] = acc[m][n][r];
    }
  }
}

// ---------------------------------------------------------------------------
extern "C" void kernel_launch(void* const* d_in, const int* in_sizes, int n_in,
                              void* d_out, int out_size, void* d_ws, size_t ws_size,
                              hipStream_t stream) {
  const float* x  = (const float*)d_in[0];
  const float* W1 = (const float*)d_in[1];
  const float* b1 = (const float*)d_in[2];
  const float* W2 = (const float*)d_in[3];
  const float* b2 = (const float*)d_in[4];
  const float* W3 = (const float*)d_in[5];
  const float* b3 = (const float*)d_in[6];
  float* C = (float*)d_out;

  // workspace: [0, 8KB) = W2b bf16 [32][128]; [16KB, 16KB+8MB) = A bf16 [N][N]
  __hip_bfloat16* W2b = (__hip_bfloat16*)d_ws;
  __hip_bfloat16* A   = (__hip_bfloat16*)((char*)d_ws + 16384);

  w2_to_bf16<<<dim3(16), dim3(256), 0, stream>>>(W2, W2b);
  build_A_mfma<<<dim3(N / 16, N / 16), dim3(256), 0, stream>>>(x, W1, b1, W2b, b2, W3, b3, A);
  gemm_ata<<<dim3(N / 128, N / 128), dim3(256), 0, stream>>>(A, C);
}

// Round 4
// 178.972 us; speedup vs baseline: 2.5382x; 1.2256x over previous
//
#include <hip/hip_runtime.h>
#include <hip/hip_bf16.h>

#define N 2048

using f32x4  = __attribute__((ext_vector_type(4))) float;
using short8 = __attribute__((ext_vector_type(8))) short;
using uint4v = __attribute__((ext_vector_type(4))) unsigned int;

// async global->LDS, 16B per lane; LDS dest = wave-uniform base + lane*16
#define GLOAD_LDS16(dst, src)                                                        \
  __builtin_amdgcn_global_load_lds((const __attribute__((address_space(1))) void*)(src), \
                                   (__attribute__((address_space(3))) void*)(dst), 16, 0, 0)

// ---------------------------------------------------------------------------
// Kernel 0: prep.  W2 -> bf16 [32][128]; W1,b1 -> pre-scaled by -log2(e) so
// the inner loop computes t' = -log2e*(w1a*xi + w1b*xj + b1) with 2 fma and
// feeds v_exp_f32 (2^t' = e^-t) directly.
// ---------------------------------------------------------------------------
__global__ void prep(const float* __restrict__ W2, const float* __restrict__ W1,
                     const float* __restrict__ b1,
                     __hip_bfloat16* __restrict__ W2b,
                     float* __restrict__ W1n, float* __restrict__ b1n) {
  const float c = -1.4426950408889634f;  // -log2(e)
  int t = blockIdx.x * 256 + threadIdx.x;   // 4096 threads
  W2b[t] = __float2bfloat16(W2[t]);
  if (t < 256) W1n[t] = W1[t] * c;
  if (t < 128) b1n[t] = b1[t] * c;
}

// ---------------------------------------------------------------------------
// Kernel 0b: zero A (8 MB) with 16B stores.
// ---------------------------------------------------------------------------
__global__ void zero_A(uint4v* __restrict__ A4) {
  A4[blockIdx.x * 256 + threadIdx.x] = (uint4v){0u, 0u, 0u, 0u};
}

// ---------------------------------------------------------------------------
// Kernel 1: build A = K^T (bf16) with MFMA layer-2.  1D triangular grid:
// block t -> (bi <= bj), 16(i) x 16(j) pair tile, 4 waves, wave w owns
// j = j0+4w..j0+4w+3.  Lane l computes h for its own A-frag slots
// {row=l&15, k=(l>>4)*8+e}.
// ---------------------------------------------------------------------------
__global__ __launch_bounds__(256) void build_A_mfma(
    const float* __restrict__ x,
    const float* __restrict__ W1n,             // [128][2], pre-scaled -log2e
    const float* __restrict__ b1n,             // [128],    pre-scaled -log2e
    const __hip_bfloat16* __restrict__ W2b,    // [32][128] bf16
    const float* __restrict__ b2,              // [32]
    const float* __restrict__ W3,              // [32]
    const float* __restrict__ b3,              // [1]
    __hip_bfloat16* __restrict__ A)            // [N][N], A[j][i]
{
  // decode linear upper-tri block id: t = bj*(bj+1)/2 + bi, bi <= bj
  const int t = blockIdx.x;
  int bj = (int)((sqrtf(8.0f * (float)t + 1.0f) - 1.0f) * 0.5f);
  while ((bj + 1) * (bj + 2) / 2 <= t) ++bj;
  while (bj * (bj + 1) / 2 > t) --bj;
  const int bi = t - bj * (bj + 1) / 2;

  const int i0 = bi * 16, j0 = bj * 16;
  const int tid = threadIdx.x;

  __shared__ float w1s[256];   // [k][2] pre-scaled
  __shared__ float b1s[128];
  w1s[tid] = W1n[tid & 255];
  if (tid < 128) b1s[tid] = b1n[tid];
  __syncthreads();

  const int w  = tid >> 6;
  const int l  = tid & 63;
  const int lm = l & 15;       // A-frag row (i-slot) / C col (o)
  const int lk = l >> 4;       // k-block-of-8 / C row-group

  const float xi = x[i0 + lm];
  float xj[4];
#pragma unroll
  for (int m = 0; m < 4; ++m) xj[m] = x[j0 + w * 4 + m];

  // W2 fragments (B^T row-major): lane holds W2[o=g*16+lm][kb*32+lk*8 .. +7]
  short8 wf[2][4];
#pragma unroll
  for (int g = 0; g < 2; ++g)
#pragma unroll
    for (int kb = 0; kb < 4; ++kb)
      wf[g][kb] = *(const short8*)(W2b + (g * 16 + lm) * 128 + kb * 32 + lk * 8);

  const float b2v[2] = {b2[lm], b2[16 + lm]};
  f32x4 acc[4][2];
#pragma unroll
  for (int m = 0; m < 4; ++m)
#pragma unroll
    for (int g = 0; g < 2; ++g)
      acc[m][g] = (f32x4){b2v[g], b2v[g], b2v[g], b2v[g]};

#pragma unroll
  for (int kb = 0; kb < 4; ++kb) {
    // xi-dependent half of layer 1, shared across the 4 j's of this wave-slot
    float base[8], w1b_[8];
#pragma unroll
    for (int e = 0; e < 8; ++e) {
      const int k = kb * 32 + lk * 8 + e;
      base[e]  = fmaf(w1s[2 * k], xi, b1s[k]);
      w1b_[e]  = w1s[2 * k + 1];
    }
#pragma unroll
    for (int m = 0; m < 4; ++m) {
      uint4v pk;
#pragma unroll
      for (int e2 = 0; e2 < 4; ++e2) {
        // h = sigmoid(t_orig) = 1/(1 + 2^t'),  t' = -log2e * t_orig
        const float t0 = fmaf(w1b_[2 * e2],     xj[m], base[2 * e2]);
        const float t1 = fmaf(w1b_[2 * e2 + 1], xj[m], base[2 * e2 + 1]);
        const float h0 = __builtin_amdgcn_rcpf(1.0f + __builtin_amdgcn_exp2f(t0));
        const float h1 = __builtin_amdgcn_rcpf(1.0f + __builtin_amdgcn_exp2f(t1));
        const unsigned u0 = __builtin_bit_cast(unsigned, h0) + 0x8000u;  // round-half-up
        const unsigned u1 = __builtin_bit_cast(unsigned, h1) + 0x8000u;
        pk[e2] = __builtin_amdgcn_perm(u1, u0, 0x07060302u);  // [hi16(u1)|hi16(u0)]
      }
      const short8 af = __builtin_bit_cast(short8, pk);
      acc[m][0] = __builtin_amdgcn_mfma_f32_16x16x32_bf16(af, wf[0][kb], acc[m][0], 0, 0, 0);
      acc[m][1] = __builtin_amdgcn_mfma_f32_16x16x32_bf16(af, wf[1][kb], acc[m][1], 0, 0, 0);
    }
  }

  // Epilogue: v = b3 + sum_o relu(layer2[pair][o]) * W3[o]
  // C/D: row(pair) = lk*4 + r, col(o) = lm (+16 for g=1)
  const float w3a = W3[lm], w3b = W3[16 + lm];
  const float b3v = b3[0];
  const int   rsel = l & 3;

#pragma unroll
  for (int m = 0; m < 4; ++m) {
    const int j = j0 + w * 4 + m;
    float v[4];
#pragma unroll
    for (int r = 0; r < 4; ++r) {
      float s = fmaf(fmaxf(acc[m][0][r], 0.0f), w3a,
                     fmaxf(acc[m][1][r], 0.0f) * w3b);
      s += __shfl_xor(s, 1);
      s += __shfl_xor(s, 2);
      s += __shfl_xor(s, 4);
      s += __shfl_xor(s, 8);
      v[r] = s + b3v;
    }
    const float sv = rsel == 0 ? v[0] : rsel == 1 ? v[1] : rsel == 2 ? v[2] : v[3];
    const int i = i0 + lk * 4 + rsel;
    if (lm < 4 && i <= j)
      A[(size_t)j * N + i] = __float2bfloat16(sv);
  }
}

// ---------------------------------------------------------------------------
// Kernel 2: C = A * A^T  (NT GEMM, both operands = A, row-major bf16).
// 64x64 tiles -> grid 32x32 = 1024 blocks = 4/CU (load balance under the
// triangular k-clip; max block 64 ktiles < 89 ktiles/CU average).
// 4 waves (2x2), each 32x32 out; BK=32; global_load_lds width 16.
// ---------------------------------------------------------------------------
__global__ __launch_bounds__(256) void gemm_ata(
    const __hip_bfloat16* __restrict__ A, float* __restrict__ C)
{
  __shared__ __align__(16) __hip_bfloat16 As[64 * 32];  // 4 KB
  __shared__ __align__(16) __hip_bfloat16 Bs[64 * 32];  // 4 KB

  const int m0 = blockIdx.y * 64;
  const int n0 = blockIdx.x * 64;
  const int tid = threadIdx.x;
  const int w  = tid >> 6;
  const int l  = tid & 63;
  const int wr = (w >> 1) * 32;
  const int wc = (w & 1) * 32;
  const int lm = l & 15;
  const int lk = l >> 4;

  f32x4 acc[2][2];
#pragma unroll
  for (int m = 0; m < 2; ++m)
#pragma unroll
    for (int n = 0; n < 2; ++n)
      acc[m][n] = (f32x4){0.f, 0.f, 0.f, 0.f};

  const int mn = m0 < n0 ? m0 : n0;
  const int ktiles = (mn + 64) >> 5;   // nonzero k <= min(m0,n0)+63

  // staging: wave w stages rows [16w,16w+16) of As and Bs (1KB each)
  const int srow = 16 * w + (l >> 2);
  const int scol = (l & 3) * 8;

  for (int kt = 0; kt < ktiles; ++kt) {
    const int k0 = kt * 32;
    __syncthreads();
    GLOAD_LDS16(As + 16 * w * 32, A + (size_t)(m0 + srow) * N + k0 + scol);
    GLOAD_LDS16(Bs + 16 * w * 32, A + (size_t)(n0 + srow) * N + k0 + scol);
    __syncthreads();

    short8 af[2], bfr[2];
#pragma unroll
    for (int m = 0; m < 2; ++m)
      af[m] = *(const short8*)(As + (wr + m * 16 + lm) * 32 + lk * 8);
#pragma unroll
    for (int n = 0; n < 2; ++n)
      bfr[n] = *(const short8*)(Bs + (wc + n * 16 + lm) * 32 + lk * 8);

#pragma unroll
    for (int m = 0; m < 2; ++m)
#pragma unroll
      for (int n = 0; n < 2; ++n)
        acc[m][n] = __builtin_amdgcn_mfma_f32_16x16x32_bf16(af[m], bfr[n], acc[m][n], 0, 0, 0);
  }

  // C/D layout: col = lane&15, row = (lane>>4)*4 + reg
#pragma unroll
  for (int m = 0; m < 2; ++m) {
    const int row = m0 + wr + m * 16 + lk * 4;
#pragma unroll
    for (int n = 0; n < 2; ++n) {
      const int col = n0 + wc + n * 16 + lm;
#pragma unroll
      for (int r = 0; r < 4; ++r)
        C[(size_t)(row + r) * N + col] = acc[m][n][r];
    }
  }
}

// ---------------------------------------------------------------------------
extern "C" void kernel_launch(void* const* d_in, const int* in_sizes, int n_in,
                              void* d_out, int out_size, void* d_ws, size_t ws_size,
                              hipStream_t stream) {
  const float* x  = (const float*)d_in[0];
  const float* W1 = (const float*)d_in[1];
  const float* b1 = (const float*)d_in[2];
  const float* W2 = (const float*)d_in[3];
  const float* b2 = (const float*)d_in[4];
  const float* W3 = (const float*)d_in[5];
  const float* b3 = (const float*)d_in[6];
  float* C = (float*)d_out;

  // ws: [0,8K) W2b bf16; [8K,9K) W1n; [12K,12.5K) b1n; [16K,16K+8M) A bf16
  __hip_bfloat16* W2b = (__hip_bfloat16*)d_ws;
  float* W1n = (float*)((char*)d_ws + 8192);
  float* b1n = (float*)((char*)d_ws + 12288);
  __hip_bfloat16* A = (__hip_bfloat16*)((char*)d_ws + 16384);

  prep<<<dim3(16), dim3(256), 0, stream>>>(W2, W1, b1, W2b, W1n, b1n);
  zero_A<<<dim3(2048), dim3(256), 0, stream>>>((uint4v*)A);
  build_A_mfma<<<dim3(8256), dim3(256), 0, stream>>>(x, W1n, b1n, W2b, b2, W3, b3, A);
  gemm_ata<<<dim3(32, 32), dim3(256), 0, stream>>>(A, C);
}